// Round 7
// baseline (473.275 us; speedup 1.0000x reference)
//
#include <hip/hip_runtime.h>

typedef unsigned int uint32;
typedef _Float16 f16;
typedef _Float16 f16x8 __attribute__((ext_vector_type(8)));
typedef float f32x4 __attribute__((ext_vector_type(4)));
typedef unsigned short u16x8 __attribute__((ext_vector_type(8)));

#define B_SZ 4
#define T_SZ 4096
#define DMODEL 512
#define NHEAD 8
#define DH 64
#define NHASH 4
#define BH (B_SZ*NHEAD)      // 32
#define NBUCK 256
#define TOT (NHASH*T_SZ)     // 16384
#define M_TOK (B_SZ*T_SZ)    // 16384

#define KSTRIDE 72           // f16 elems per LDS row (128B data + 16B pad)
#define PSTRIDE 136

// split-f16 MFMA hash-score worst-case error ~4e-5*rms; keep >=35x margin.
#define AMB_TAU 1.5e-3f

// ---------------- KPREP: fused {zero cnt, W split, rot split, query split} ---
// blockIdx ranges: [0,3072) = kw_t, [3072,3104) = kr_t, [3104,7200) = k1a.
__global__ __launch_bounds__(256) void kprep(
    const float* __restrict__ Wqk, const float* __restrict__ Wv,
    const float* __restrict__ Wout, f16* __restrict__ Wth, f16* __restrict__ Wtl,
    const float* __restrict__ rot, f16* __restrict__ rotTh, f16* __restrict__ rotTl,
    const float* __restrict__ qin, f16* __restrict__ Ah, f16* __restrict__ Al,
    int* __restrict__ amb_cnt)
{
  int bx = blockIdx.x;
  if (bx == 0 && threadIdx.x == 0) *amb_cnt = 0;
  if (bx < 3072){
    int gid = bx*256 + threadIdx.x;
    int n = gid >> 9, k = gid & 511;
    int sel = n >> 9, col = n & 511;
    const float* src = (sel==0)? Wqk : (sel==1)? Wv : Wout;
    float v = src[(size_t)k*512 + col];
    f16 h = (f16)v;
    Wth[gid] = h;
    Wtl[gid] = (f16)(v - (float)h);
  } else if (bx < 3104){
    int gid = (bx - 3072)*256 + threadIdx.x;   // [0, 128*64)
    int n = gid >> 6, dd = gid & 63;
    float v = rot[dd*128 + n];
    f16 h = (f16)v;
    rotTh[gid] = h;
    rotTl[gid] = (f16)(v - (float)h);
  } else {
    size_t gid = (size_t)(bx - 3104)*256 + threadIdx.x;
    const float4* src = (const float4*)(qin) + gid*2;
    float4 x0 = src[0], x1 = src[1];
    float v[8] = {x0.x,x0.y,x0.z,x0.w, x1.x,x1.y,x1.z,x1.w};
    f16x8 h, l;
    #pragma unroll
    for (int e=0;e<8;e++){ f16 hh=(f16)v[e]; h[e]=hh; l[e]=(f16)(v[e]-(float)hh); }
    ((f16x8*)Ah)[gid] = h;
    ((f16x8*)Al)[gid] = l;
  }
}

// ---------------- G1: split-f16 MFMA GEMM  qk|v = queries @ [Wqk|Wv] ---------
__global__ __launch_bounds__(256) void g_qkv(const f16* __restrict__ Ah,
    const f16* __restrict__ Al, const f16* __restrict__ Wth, const f16* __restrict__ Wtl,
    f16* __restrict__ qk16, f16* __restrict__ qkl, f16* __restrict__ v16)
{
  __shared__ f16 ah[128*KSTRIDE], al[128*KSTRIDE], bh[128*KSTRIDE], bl[128*KSTRIDE];
  int tid = threadIdx.x;
  int m0 = blockIdx.x*128, n0 = blockIdx.y*128;
  int w = tid >> 6, lane = tid & 63;
  int wm = w >> 1, wn = w & 1;
  int c_lane = lane & 15, quad = lane >> 4;

  f32x4 acc[4][4];
  #pragma unroll
  for (int mi=0;mi<4;mi++)
    #pragma unroll
    for (int ni=0;ni<4;ni++) acc[mi][ni] = (f32x4){0.f,0.f,0.f,0.f};

  int sr = tid >> 1, sc = (tid & 1) * 32;
  for (int kc=0; kc<8; kc++){
    int k0 = kc*64;
    {
      const f16x8* pah = (const f16x8*)(Ah + (size_t)(m0+sr)*512 + k0 + sc);
      const f16x8* pal = (const f16x8*)(Al + (size_t)(m0+sr)*512 + k0 + sc);
      const f16x8* pbh = (const f16x8*)(Wth + (size_t)(n0+sr)*512 + k0 + sc);
      const f16x8* pbl = (const f16x8*)(Wtl + (size_t)(n0+sr)*512 + k0 + sc);
      f16x8* dah = (f16x8*)&ah[sr*KSTRIDE + sc];
      f16x8* dal = (f16x8*)&al[sr*KSTRIDE + sc];
      f16x8* dbh = (f16x8*)&bh[sr*KSTRIDE + sc];
      f16x8* dbl = (f16x8*)&bl[sr*KSTRIDE + sc];
      #pragma unroll
      for (int i=0;i<4;i++){ dah[i]=pah[i]; dal[i]=pal[i]; dbh[i]=pbh[i]; dbl[i]=pbl[i]; }
    }
    __syncthreads();
    f16x8 fah[4][2], fal[4][2], fbh[4][2], fbl[4][2];
    #pragma unroll
    for (int i=0;i<4;i++)
      #pragma unroll
      for (int kb=0;kb<2;kb++){
        int ma = (wm*64 + i*16 + c_lane)*KSTRIDE + kb*32 + quad*8;
        int nb = (wn*64 + i*16 + c_lane)*KSTRIDE + kb*32 + quad*8;
        fah[i][kb] = *(const f16x8*)&ah[ma];
        fal[i][kb] = *(const f16x8*)&al[ma];
        fbh[i][kb] = *(const f16x8*)&bh[nb];
        fbl[i][kb] = *(const f16x8*)&bl[nb];
      }
    #pragma unroll
    for (int kb=0;kb<2;kb++)
      #pragma unroll
      for (int p=0;p<3;p++)
        #pragma unroll
        for (int mi=0;mi<4;mi++)
          #pragma unroll
          for (int ni=0;ni<4;ni++){
            f16x8 a = (p==2)? fal[mi][kb] : fah[mi][kb];
            f16x8 b = (p==1)? fbl[ni][kb] : fbh[ni][kb];
            acc[mi][ni] = __builtin_amdgcn_mfma_f32_16x16x32_f16(a, b, acc[mi][ni], 0,0,0);
          }
    __syncthreads();
  }

  // epilogue: n<512 -> qk16(hi)+qkl(lo); n>=512 -> v16
  #pragma unroll
  for (int mi=0;mi<4;mi++)
    #pragma unroll
    for (int ni=0;ni<4;ni++)
      #pragma unroll
      for (int r=0;r<4;r++){
        int n = n0 + wn*64 + ni*16 + c_lane;
        int tok = m0 + wm*64 + mi*16 + quad*4 + r;
        float val = acc[mi][ni][r];
        int b = tok >> 12, tp = tok & 4095;
        if (n < 512){
          int head = n >> 6, dd = n & 63;
          size_t idx = ((size_t)(b*NHEAD+head)*T_SZ + tp)*DH + dd;
          f16 hv = (f16)val;
          qk16[idx] = hv;
          qkl[idx]  = (f16)(val - (float)hv);
        } else {
          int j = n - 512, head = j >> 6, dd = j & 63;
          size_t idx = ((size_t)(b*NHEAD+head)*T_SZ + tp)*DH + dd;
          v16[idx] = (f16)val;
        }
      }
}

// ---------------- G2: fused round-combine + split-f16 GEMM  out = X @ Wout ----
// v5: BM 128 -> 64. R4/R6 lesson: the limiter was GRID (512 blocks = 2/CU),
// not LDS -- halving LDS changed nothing. Tile 64x128 -> 1024 blocks = 4/CU,
// 16 waves/CU (2x TLP). Wave owns 32x64 (acc 2x4). LDS 18432B (A only);
// B-direct from L2. Same kc/kb/p MFMA order per output -> bit-identical.
__global__ __launch_bounds__(256) void g_out(const float* __restrict__ lse,
    const f16* __restrict__ o_f16, const f16* __restrict__ Wth, const f16* __restrict__ Wtl,
    const float* __restrict__ bout, float* __restrict__ out)
{
  __shared__ f16 ah[64*KSTRIDE], al[64*KSTRIDE];
  int tid = threadIdx.x;
  int m0 = blockIdx.x*64, n0 = blockIdx.y*128;
  int w = tid >> 6, lane = tid & 63;
  int wm = w >> 1, wn = w & 1;
  int c_lane = lane & 15, quad = lane >> 4;
  const f16* Bh_base = Wth + (size_t)1024*512;   // Wout section
  const f16* Bl_base = Wtl + (size_t)1024*512;

  f32x4 acc[2][4];
  #pragma unroll
  for (int mi=0;mi<2;mi++)
    #pragma unroll
    for (int ni=0;ni<4;ni++) acc[mi][ni] = (f32x4){0.f,0.f,0.f,0.f};

  int sr = tid >> 2, sc = (tid & 3) * 16;      // 4 threads per row, 16 elems each
  int tok = m0 + sr;
  int tb = tok >> 12, tt = tok & 4095;

  for (int kc=0; kc<8; kc++){
    int k0 = kc*64;
    {
      // ---- fused k5: combine 4 hash rounds for head kc, rows tok ----
      size_t lbase = ((size_t)(tb*NHEAD + kc)*NHASH)*T_SZ + tt;
      float l0 = lse[lbase];
      float l1 = lse[lbase + T_SZ];
      float l2 = lse[lbase + 2*T_SZ];
      float l3 = lse[lbase + 3*T_SZ];
      float M = fmaxf(fmaxf(l0,l1), fmaxf(l2,l3));
      float e0 = __expf(l0-M), e1 = __expf(l1-M), e2 = __expf(l2-M), e3 = __expf(l3-M);
      float inv = 1.0f/(e0+e1+e2+e3);
      float w0=e0*inv, w1=e1*inv, w2=e2*inv, w3=e3*inv;
      const f16x8* r0 = (const f16x8*)(o_f16 + lbase*DH + sc);
      const f16x8* r1 = (const f16x8*)(o_f16 + (lbase + (size_t)T_SZ)*DH + sc);
      const f16x8* r2 = (const f16x8*)(o_f16 + (lbase + (size_t)2*T_SZ)*DH + sc);
      const f16x8* r3 = (const f16x8*)(o_f16 + (lbase + (size_t)3*T_SZ)*DH + sc);
      f16x8* dah = (f16x8*)&ah[sr*KSTRIDE + sc];
      f16x8* dal = (f16x8*)&al[sr*KSTRIDE + sc];
      #pragma unroll
      for (int i=0;i<2;i++){
        f16x8 a = r0[i], bb = r1[i], cc = r2[i], dd = r3[i];
        f16x8 ho, lo;
        #pragma unroll
        for (int e=0;e<8;e++){
          float res = w0*(float)a[e] + w1*(float)bb[e] + w2*(float)cc[e] + w3*(float)dd[e];
          f16 hh = (f16)res;
          ho[e] = hh; lo[e] = (f16)(res - (float)hh);
        }
        dah[i] = ho; dal[i] = lo;
      }
    }
    __syncthreads();
    f16x8 fah[2][2], fal[2][2], fbh[4][2], fbl[4][2];
    #pragma unroll
    for (int mi=0;mi<2;mi++){
      int ma = (wm*32 + mi*16 + c_lane)*KSTRIDE;
      #pragma unroll
      for (int kb=0;kb<2;kb++){
        fah[mi][kb] = *(const f16x8*)&ah[ma + kb*32 + quad*8];
        fal[mi][kb] = *(const f16x8*)&al[ma + kb*32 + quad*8];
      }
    }
    #pragma unroll
    for (int ni=0;ni<4;ni++){
      const f16* brh = Bh_base + (size_t)(n0 + wn*64 + ni*16 + c_lane)*512 + k0;
      const f16* brl = Bl_base + (size_t)(n0 + wn*64 + ni*16 + c_lane)*512 + k0;
      #pragma unroll
      for (int kb=0;kb<2;kb++){
        fbh[ni][kb] = *(const f16x8*)&brh[kb*32 + quad*8];
        fbl[ni][kb] = *(const f16x8*)&brl[kb*32 + quad*8];
      }
    }
    #pragma unroll
    for (int kb=0;kb<2;kb++)
      #pragma unroll
      for (int p=0;p<3;p++)
        #pragma unroll
        for (int mi=0;mi<2;mi++)
          #pragma unroll
          for (int ni=0;ni<4;ni++){
            f16x8 a = (p==2)? fal[mi][kb] : fah[mi][kb];
            f16x8 b = (p==1)? fbl[ni][kb] : fbh[ni][kb];
            acc[mi][ni] = __builtin_amdgcn_mfma_f32_16x16x32_f16(a, b, acc[mi][ni], 0,0,0);
          }
    __syncthreads();
  }

  #pragma unroll
  for (int mi=0;mi<2;mi++)
    #pragma unroll
    for (int ni=0;ni<4;ni++){
      int n = n0 + wn*64 + ni*16 + c_lane;
      float bn = bout[n];
      #pragma unroll
      for (int r=0;r<4;r++){
        int tk2 = m0 + wm*32 + mi*16 + quad*4 + r;
        out[(size_t)tk2*512 + n] = acc[mi][ni][r] + bn;
      }
    }
}

// ---------------- K2: LSH hashing, rot-as-A MFMA + in-lane argmax epilogue ----
__global__ __launch_bounds__(256, 4) void k2_mfma(const f16* __restrict__ qkh,
    const f16* __restrict__ qkl, const f16* __restrict__ rotTh, const f16* __restrict__ rotTl,
    unsigned short* __restrict__ bucket,
    int* __restrict__ amb_list, int* __restrict__ amb_cnt)
{
  int tid = threadIdx.x;
  int w = tid >> 6, lane = tid & 63;
  int c_lane = lane & 15, quad = lane >> 4;
  int tok0 = (blockIdx.x*4 + w)*16;            // 16 tokens per wave
  size_t rowb = (size_t)(tok0 + c_lane)*64;

  // B fragments: token hi/lo (col = token = c_lane, k = kb*32 + quad*8 + e)
  f16x8 tbh[2], tbl[2];
  #pragma unroll
  for (int kb=0;kb<2;kb++){
    tbh[kb] = *(const f16x8*)&qkh[rowb + kb*32 + quad*8];
    tbl[kb] = *(const f16x8*)&qkl[rowb + kb*32 + quad*8];
  }

  f32x4 acc[8];
  #pragma unroll
  for (int mi=0;mi<8;mi++) acc[mi] = (f32x4){0.f,0.f,0.f,0.f};

  // A fragments: rot rows j = mi*16 + c_lane (L1-resident, 32KB total)
  #pragma unroll
  for (int mi=0;mi<8;mi++){
    int aoff = (mi*16 + c_lane)*64;
    #pragma unroll
    for (int kb=0;kb<2;kb++){
      f16x8 arh = *(const f16x8*)&rotTh[aoff + kb*32 + quad*8];
      f16x8 arl = *(const f16x8*)&rotTl[aoff + kb*32 + quad*8];
      acc[mi] = __builtin_amdgcn_mfma_f32_16x16x32_f16(arh, tbh[kb], acc[mi], 0,0,0);
      acc[mi] = __builtin_amdgcn_mfma_f32_16x16x32_f16(arl, tbh[kb], acc[mi], 0,0,0);
      acc[mi] = __builtin_amdgcn_mfma_f32_16x16x32_f16(arh, tbl[kb], acc[mi], 0,0,0);
    }
  }

  // lane (c_lane, quad) holds scores s[j] for token tok0+c_lane,
  // j = mi*16 + quad*4 + r  (mi = 0..7, r = 0..3)
  int tokg = tok0 + c_lane;
  int bhh = tokg >> 12, t = tokg & 4095;

  #pragma unroll
  for (int h=0; h<4; h++){
    float m1 = -1e30f, m2 = -1e30f, ssq = 0.f; int b1 = 0;
    #pragma unroll
    for (int u=0; u<8; u++){
      float v = acc[2*h + (u>>2)][u&3];
      int bidd = (u>>2)*16 + quad*4 + (u&3);   // within-hash index [0,32)
      ssq += v*v;
      if (v > m1){ m2=m1; m1=v; b1=bidd; } else if (v > m2) m2=v;
      float nv = -v;
      if (nv > m1){ m2=m1; m1=nv; b1=bidd+32; } else if (nv > m2) m2=nv;
    }
    // cross-quad reduce (lane bits 4,5)
    #pragma unroll
    for (int d2=16; d2<64; d2<<=1){
      float om1 = __shfl_xor(m1, d2);
      float om2 = __shfl_xor(m2, d2);
      int   ob1 = __shfl_xor(b1, d2);
      ssq += __shfl_xor(ssq, d2);
      if (om1 > m1){ m2 = fmaxf(m1, om2); m1 = om1; b1 = ob1; }
      else          { m2 = fmaxf(m2, om1); }
    }
    if (quad == 0){
      float rms = sqrtf(ssq * (1.0f/32.0f));
      if (m1 - m2 < AMB_TAU * rms){
        int idx = atomicAdd(amb_cnt, 1);
        amb_list[idx] = (bhh<<14) | (h<<12) | t;
      } else {
        bucket[((bhh*NHASH + h)<<12) + t] = (unsigned short)(b1 + (h<<6));
      }
    }
  }
}

// ---------------- K2fix: exact f64 recompute, 4-way d-parallel ----------------
__global__ __launch_bounds__(256) void k2_fix(const float* __restrict__ qin,
    const float* __restrict__ Wqk, const float* __restrict__ rot,
    const int* __restrict__ amb_list, const int* __restrict__ amb_cnt,
    unsigned short* __restrict__ bucket)
{
  __shared__ __align__(16) float qs[512];
  __shared__ double part[4][64];
  __shared__ double qk64[64];
  __shared__ double accs[32];
  int n = *amb_cnt;
  int tid = threadIdx.x;
  int j = tid & 63, chunk = tid >> 6;
  for (int it = blockIdx.x; it < n; it += gridDim.x){
    int gid = amb_list[it];
    int t = gid & (T_SZ-1);
    int h = (gid >> 12) & 3;
    int bh = gid >> 14;
    int b = bh >> 3, head = bh & 7;
    if (tid < 128)
      *(float4*)&qs[tid*4] = ((const float4*)(qin + ((size_t)b*T_SZ + t)*DMODEL))[tid];
    __syncthreads();
    const float* wcol = Wqk + head*64 + j;
    int d0 = chunk*128;
    double s = 0.0;
    #pragma unroll 16
    for (int d=0; d<128; d++)
      s += (double)qs[d0+d] * (double)wcol[(size_t)(d0+d)*512];
    part[chunk][j] = s;
    __syncthreads();
    if (tid < 64)
      qk64[tid] = ((part[0][tid] + part[1][tid]) + part[2][tid]) + part[3][tid];
    __syncthreads();
    if (tid < 32){
      double a = 0.0;
      #pragma unroll 16
      for (int f=0; f<64; f++)
        a += qk64[f] * (double)rot[f*(NHASH*32) + h*32 + tid];
      accs[tid] = a;
    }
    __syncthreads();
    if (tid == 0){
      double best = accs[0]; int bk = 0;
      for (int k=1;k<64;k++){
        double vv = (k<32)? accs[k] : -accs[k-32];
        if (vv > best){ best = vv; bk = k; }
      }
      bucket[((bh*NHASH + h)<<12) + t] = (unsigned short)(bk + (h<<6));
    }
    __syncthreads();
  }
}

// ---------------- K3: LDS histogram from bucket + exclusive prefix scan -------
__global__ __launch_bounds__(256) void k3_scan(const unsigned short* __restrict__ bucket,
    int* __restrict__ starts){
  __shared__ int s[256];
  int bh = blockIdx.x, tid = threadIdx.x;
  s[tid] = 0;
  __syncthreads();
  const u16x8* b8 = (const u16x8*)(bucket + ((size_t)bh*NHASH << 12));
  for (int i = tid; i < 2048; i += 256){   // 16384 u16 = 2048 x u16x8
    u16x8 x = b8[i];
    #pragma unroll
    for (int e=0;e<8;e++) atomicAdd(&s[x[e]], 1);
  }
  __syncthreads();
  int v = s[tid];
  __syncthreads();
  for (int off=1; off<256; off<<=1){
    int a = (tid >= off) ? s[tid-off] : 0;
    __syncthreads();
    s[tid] += a;
    __syncthreads();
  }
  starts[bh*256 + tid] = s[tid] - v;
}

// ---------------- K3b: stable counting-sort scatter ----------------
__global__ __launch_bounds__(64) void k3b_scatter(const unsigned short* __restrict__ bucket,
    const int* __restrict__ starts, int* __restrict__ st)
{
  int blk = blockIdx.x;
  int bh = blk >> 8; int g = blk & 255; int h = g >> 6;
  int lane = threadIdx.x;
  const unsigned short* brow = bucket + ((bh*NHASH + h)<<12);
  int base = starts[bh*NBUCK + g];
  for (int step=0; step<64; step++){
    int t = step*64 + lane;
    bool pred = (brow[t] == (unsigned short)g);
    unsigned long long mask = __ballot(pred);
    if (pred){
      int off = __popcll(mask & ((1ull<<lane) - 1ull));
      st[bh*TOT + base + off] = t;
    }
    base += __popcll(mask);
  }
}

// ---------------- K4: MFMA chunked LSH attention ------------------------------
// 4 cooperative waves per chunk (wave w owns query sub-tile mi=w).
// 36864B LDS -> 4 blocks/CU at 256 thr = 16 waves/CU. XCD-aware swizzle.
__global__ __launch_bounds__(256, 4) void k4_attn(const f16* __restrict__ qk16,
    const f16* __restrict__ v16, const int* __restrict__ st,
    float* __restrict__ lse_out, f16* __restrict__ o_out)
{
  __shared__ __align__(16) char smem[36864];
  f16*   k_lds   = (f16*)smem;                 // 128 x KSTRIDE (alias p_lds)
  f16*   p_lds   = (f16*)smem;                 // 64 x PSTRIDE
  f16*   vT      = (f16*)(smem + 18432);       // 64 x PSTRIDE (d-major)
  float* invnorm = (float*)(smem + 35840);
  int*   kv_t    = (int*)(smem + 36352);

  int bid = blockIdx.x;
  int swz = (bid & 7) * 1024 + (bid >> 3);     // bijective: 8192 = 8*1024
  int bh = swz >> 8; int c = swz & 255;
  int h = c >> 6; int cp = (c + 255) & 255;
  int tid = threadIdx.x;
  int w = tid >> 6, lane = tid & 63;
  int c_lane = lane & 15, quad = lane >> 4;
  const int* strow = st + bh*TOT;

  // ---- load phase: threads 0..127, one full K/V row each
  if (tid < 128){
    int row = tid;
    int slot = (row < 64) ? (c*64 + row) : (cp*64 + row - 64);
    int t = strow[slot];
    kv_t[row] = t;
    const f16x8* kr = (const f16x8*)(qk16 + ((size_t)bh*T_SZ + t)*DH);
    const f16x8* vr = (const f16x8*)(v16  + ((size_t)bh*T_SZ + t)*DH);
    f16x8 kv[8], vv[8];
    float ss = 0.f;
    #pragma unroll
    for (int i=0;i<8;i++){
      f16x8 x = kr[i]; kv[i] = x;
      vv[i] = vr[i];
      #pragma unroll
      for (int e=0;e<8;e++){ float f = (float)x[e]; ss += f*f; }
    }
    invnorm[row] = 1.0f / fmaxf(sqrtf(ss), 1e-12f);
    f16x8* kd = (f16x8*)&k_lds[row*KSTRIDE];
    #pragma unroll
    for (int i=0;i<8;i++) kd[i] = kv[i];
    #pragma unroll
    for (int i=0;i<8;i++){
      #pragma unroll
      for (int e=0;e<8;e++) vT[(i*8+e)*PSTRIDE + row] = vv[i][e];
    }
  }
  __syncthreads();

  // ---- QK^T: wave w computes query sub-tile mi = w ----
  int mi = w;
  f16x8 aq[2];
  #pragma unroll
  for (int kb=0;kb<2;kb++)
    aq[kb] = *(const f16x8*)&k_lds[(mi*16 + c_lane)*KSTRIDE + kb*32 + quad*8];

  f32x4 accS[8];
  #pragma unroll
  for (int ni=0;ni<8;ni++) accS[ni] = (f32x4){0.f,0.f,0.f,0.f};

  #pragma unroll
  for (int ni=0;ni<8;ni++){
    int rowb = ni*16 + c_lane;
    f16 sc = (f16)invnorm[rowb];
    f16x8 b0 = *(const f16x8*)&k_lds[rowb*KSTRIDE + 0*32 + quad*8];
    f16x8 b1 = *(const f16x8*)&k_lds[rowb*KSTRIDE + 1*32 + quad*8];
    b0 *= sc; b1 *= sc;
    accS[ni] = __builtin_amdgcn_mfma_f32_16x16x32_f16(aq[0], b0, accS[ni], 0,0,0);
    accS[ni] = __builtin_amdgcn_mfma_f32_16x16x32_f16(aq[1], b1, accS[ni], 0,0,0);
  }

  int tq[4];
  #pragma unroll
  for (int r=0;r<4;r++) tq[r] = kv_t[mi*16 + quad*4 + r];
  int tk[8];
  #pragma unroll
  for (int ni=0;ni<8;ni++) tk[ni] = kv_t[ni*16 + c_lane];

  float mrow[4], lrow[4];
  #pragma unroll
  for (int r=0;r<4;r++){
    float mx = -1e30f;
    #pragma unroll
    for (int ni=0;ni<8;ni++){
      float s = accS[ni][r] * 0.125f;
      if (tk[ni] == tq[r]) s = -50000.0f;
      accS[ni][r] = s;
      mx = fmaxf(mx, s);
    }
    mx = fmaxf(mx, __shfl_xor(mx, 1));
    mx = fmaxf(mx, __shfl_xor(mx, 2));
    mx = fmaxf(mx, __shfl_xor(mx, 4));
    mx = fmaxf(mx, __shfl_xor(mx, 8));
    mrow[r] = mx;
    float ls = 0.f;
    #pragma unroll
    for (int ni=0;ni<8;ni++){
      float e = __expf(accS[ni][r] - mx);
      accS[ni][r] = e;
      ls += e;
    }
    ls += __shfl_xor(ls, 1);
    ls += __shfl_xor(ls, 2);
    ls += __shfl_xor(ls, 4);
    ls += __shfl_xor(ls, 8);
    lrow[r] = ls;
  }

  // all waves done reading k_lds (aliased with p_lds) before any P write
  __syncthreads();

  #pragma unroll
  for (int ni=0;ni<8;ni++)
    #pragma unroll
    for (int r=0;r<4;r++)
      p_lds[(mi*16 + quad*4 + r)*PSTRIDE + ni*16 + c_lane] = (f16)accS[ni][r];

  // wave reads only its own P rows -> no cross-wave barrier needed
  f16x8 pa[4];
  #pragma unroll
  for (int kb=0;kb<4;kb++)
    pa[kb] = *(const f16x8*)&p_lds[(mi*16 + c_lane)*PSTRIDE + kb*32 + quad*8];

  size_t rowbase = (size_t)(bh*NHASH + h)*T_SZ;
  #pragma unroll
  for (int ni2=0;ni2<4;ni2++){
    f16x8 bv[4];
    #pragma unroll
    for (int kb=0;kb<4;kb++)
      bv[kb] = *(const f16x8*)&vT[(ni2*16 + c_lane)*PSTRIDE + kb*32 + quad*8];
    f32x4 accO = (f32x4){0.f,0.f,0.f,0.f};
    #pragma unroll
    for (int kb=0;kb<4;kb++)
      accO = __builtin_amdgcn_mfma_f32_16x16x32_f16(pa[kb], bv[kb], accO, 0,0,0);
    #pragma unroll
    for (int r=0;r<4;r++){
      float invl = 1.0f / lrow[r];
      f16* orow = o_out + (rowbase + tq[r])*DH;
      orow[ni2*16 + c_lane] = (f16)(accO[r] * invl);
    }
  }
  #pragma unroll
  for (int r=0;r<4;r++){
    if (c_lane == 0)
      lse_out[rowbase + tq[r]] = mrow[r] + logf(lrow[r]);
  }
}

// ---------------- launch ----------------
extern "C" void kernel_launch(void* const* d_in, const int* in_sizes, int n_in,
                              void* d_out, int out_size, void* d_ws, size_t ws_size,
                              hipStream_t stream) {
  const float* queries = (const float*)d_in[0];
  const float* Wqk     = (const float*)d_in[3];
  const float* Wv      = (const float*)d_in[4];
  const float* Wout    = (const float*)d_in[5];
  const float* bout    = (const float*)d_in[6];
  const float* rot     = (const float*)d_in[7];
  float* out = (float*)d_out;

  const size_t SZ_F16  = (size_t)BH*T_SZ*DH*2;        // 16 MB
  const size_t SZ_WT   = (size_t)1536*512*2;          // 1.5 MB
  const size_t SZ_ROT  = (size_t)128*64*2;            // 16 KB
  const size_t SZ_O    = (size_t)BH*NHASH*T_SZ*DH*2;  // 64 MB
  const size_t OFS_X      = 0;
  const size_t OFS_AH     = OFS_X    + 2*SZ_F16;
  const size_t OFS_AL     = OFS_AH   + SZ_F16;
  const size_t OFS_QK16   = OFS_AL   + SZ_F16;
  const size_t OFS_V16    = OFS_QK16 + SZ_F16;
  const size_t OFS_WTH    = OFS_V16  + SZ_F16;
  const size_t OFS_WTL    = OFS_WTH  + SZ_WT;
  const size_t OFS_ROTH   = OFS_WTL  + SZ_WT;
  const size_t OFS_ROTL   = OFS_ROTH + SZ_ROT;
  const size_t OFS_O      = OFS_ROTL + SZ_ROT;
  const size_t OFS_BUCKET = OFS_O    + SZ_O;
  const size_t OFS_HIST   = OFS_BUCKET + (size_t)BH*NHASH*T_SZ*2;
  const size_t OFS_STARTS = OFS_HIST   + (size_t)BH*NBUCK*4;
  const size_t OFS_ST     = OFS_STARTS + (size_t)BH*NBUCK*4;
  const size_t OFS_LSE    = OFS_ST     + (size_t)BH*TOT*4;
  const size_t OFS_AMB    = OFS_LSE    + (size_t)BH*NHASH*T_SZ*4;
  const size_t OFS_CNT    = OFS_AMB    + (size_t)BH*NHASH*T_SZ*4;
  const size_t WS_NEEDED  = OFS_CNT    + 256;
  if (ws_size < WS_NEEDED) return;

  char* ws = (char*)d_ws;
  f16*      qkl    = (f16*)(ws + OFS_X);               // lo split of qk (g_qkv/k2)
  f16*      Ah     = (f16*)(ws + OFS_AH);
  f16*      Al     = (f16*)(ws + OFS_AL);
  f16*      qk16   = (f16*)(ws + OFS_QK16);
  f16*      v16    = (f16*)(ws + OFS_V16);
  f16*      Wth    = (f16*)(ws + OFS_WTH);
  f16*      Wtl    = (f16*)(ws + OFS_WTL);
  f16*      rotTh  = (f16*)(ws + OFS_ROTH);
  f16*      rotTl  = (f16*)(ws + OFS_ROTL);
  f16*      o_f16  = (f16*)(ws + OFS_O);
  unsigned short* bucket = (unsigned short*)(ws + OFS_BUCKET);
  int*      starts = (int*)(ws + OFS_STARTS);
  int*      st     = (int*)(ws + OFS_ST);
  float*    lse    = (float*)(ws + OFS_LSE);
  int*      amb    = (int*)(ws + OFS_AMB);
  int*      cnt    = (int*)(ws + OFS_CNT);

  kprep     <<<7200, 256, 0, stream>>>(Wqk, Wv, Wout, Wth, Wtl, rot, rotTh, rotTl,
                                       queries, Ah, Al, cnt);
  g_qkv     <<<dim3(M_TOK/128, 8), 256, 0, stream>>>(Ah, Al, Wth, Wtl, qk16, qkl, v16);
  k2_mfma   <<<(BH*T_SZ)/64, 256, 0, stream>>>(qk16, qkl, rotTh, rotTl, bucket, amb, cnt);
  k2_fix    <<<2048, 256, 0, stream>>>(queries, Wqk, rot, amb, cnt, bucket);
  k3_scan   <<<BH, 256, 0, stream>>>(bucket, starts);
  k3b_scatter<<<BH*NBUCK, 64, 0, stream>>>(bucket, starts, st);
  k4_attn   <<<BH*256, 256, 0, stream>>>(qk16, v16, st, lse, o_f16);
  g_out     <<<dim3(M_TOK/64, 4), 256, 0, stream>>>(lse, o_f16, Wth, Wtl, bout, out);
}

// Round 8
// 433.888 us; speedup vs baseline: 1.0908x; 1.0908x over previous
//
#include <hip/hip_runtime.h>

typedef unsigned int uint32;
typedef _Float16 f16;
typedef _Float16 f16x8 __attribute__((ext_vector_type(8)));
typedef float f32x4 __attribute__((ext_vector_type(4)));
typedef unsigned short u16x8 __attribute__((ext_vector_type(8)));

#define B_SZ 4
#define T_SZ 4096
#define DMODEL 512
#define NHEAD 8
#define DH 64
#define NHASH 4
#define BH (B_SZ*NHEAD)      // 32
#define NBUCK 256
#define TOT (NHASH*T_SZ)     // 16384
#define M_TOK (B_SZ*T_SZ)    // 16384

#define KSTRIDE 72           // f16 elems per LDS row (128B data + 16B pad)
#define PSTRIDE 136

// split-f16 MFMA hash-score worst-case error ~4e-5*rms; keep >=35x margin.
#define AMB_TAU 1.5e-3f

// ---------------- KPREP: fused {zero cnt, W split, rot split, query split} ---
// blockIdx ranges: [0,3072) = kw_t, [3072,3104) = kr_t, [3104,7200) = k1a.
__global__ __launch_bounds__(256) void kprep(
    const float* __restrict__ Wqk, const float* __restrict__ Wv,
    const float* __restrict__ Wout, f16* __restrict__ Wth, f16* __restrict__ Wtl,
    const float* __restrict__ rot, f16* __restrict__ rotTh, f16* __restrict__ rotTl,
    const float* __restrict__ qin, f16* __restrict__ Ah, f16* __restrict__ Al,
    int* __restrict__ amb_cnt)
{
  int bx = blockIdx.x;
  if (bx == 0 && threadIdx.x == 0) *amb_cnt = 0;
  if (bx < 3072){
    int gid = bx*256 + threadIdx.x;
    int n = gid >> 9, k = gid & 511;
    int sel = n >> 9, col = n & 511;
    const float* src = (sel==0)? Wqk : (sel==1)? Wv : Wout;
    float v = src[(size_t)k*512 + col];
    f16 h = (f16)v;
    Wth[gid] = h;
    Wtl[gid] = (f16)(v - (float)h);
  } else if (bx < 3104){
    int gid = (bx - 3072)*256 + threadIdx.x;   // [0, 128*64)
    int n = gid >> 6, dd = gid & 63;
    float v = rot[dd*128 + n];
    f16 h = (f16)v;
    rotTh[gid] = h;
    rotTl[gid] = (f16)(v - (float)h);
  } else {
    size_t gid = (size_t)(bx - 3104)*256 + threadIdx.x;
    const float4* src = (const float4*)(qin) + gid*2;
    float4 x0 = src[0], x1 = src[1];
    float v[8] = {x0.x,x0.y,x0.z,x0.w, x1.x,x1.y,x1.z,x1.w};
    f16x8 h, l;
    #pragma unroll
    for (int e=0;e<8;e++){ f16 hh=(f16)v[e]; h[e]=hh; l[e]=(f16)(v[e]-(float)hh); }
    ((f16x8*)Ah)[gid] = h;
    ((f16x8*)Al)[gid] = l;
  }
}

// ---------------- G1: split-f16 MFMA GEMM  qk|v = queries @ [Wqk|Wv] ---------
__global__ __launch_bounds__(256) void g_qkv(const f16* __restrict__ Ah,
    const f16* __restrict__ Al, const f16* __restrict__ Wth, const f16* __restrict__ Wtl,
    f16* __restrict__ qk16, f16* __restrict__ qkl, f16* __restrict__ v16)
{
  __shared__ f16 ah[128*KSTRIDE], al[128*KSTRIDE], bh[128*KSTRIDE], bl[128*KSTRIDE];
  int tid = threadIdx.x;
  int m0 = blockIdx.x*128, n0 = blockIdx.y*128;
  int w = tid >> 6, lane = tid & 63;
  int wm = w >> 1, wn = w & 1;
  int c_lane = lane & 15, quad = lane >> 4;

  f32x4 acc[4][4];
  #pragma unroll
  for (int mi=0;mi<4;mi++)
    #pragma unroll
    for (int ni=0;ni<4;ni++) acc[mi][ni] = (f32x4){0.f,0.f,0.f,0.f};

  int sr = tid >> 1, sc = (tid & 1) * 32;
  for (int kc=0; kc<8; kc++){
    int k0 = kc*64;
    {
      const f16x8* pah = (const f16x8*)(Ah + (size_t)(m0+sr)*512 + k0 + sc);
      const f16x8* pal = (const f16x8*)(Al + (size_t)(m0+sr)*512 + k0 + sc);
      const f16x8* pbh = (const f16x8*)(Wth + (size_t)(n0+sr)*512 + k0 + sc);
      const f16x8* pbl = (const f16x8*)(Wtl + (size_t)(n0+sr)*512 + k0 + sc);
      f16x8* dah = (f16x8*)&ah[sr*KSTRIDE + sc];
      f16x8* dal = (f16x8*)&al[sr*KSTRIDE + sc];
      f16x8* dbh = (f16x8*)&bh[sr*KSTRIDE + sc];
      f16x8* dbl = (f16x8*)&bl[sr*KSTRIDE + sc];
      #pragma unroll
      for (int i=0;i<4;i++){ dah[i]=pah[i]; dal[i]=pal[i]; dbh[i]=pbh[i]; dbl[i]=pbl[i]; }
    }
    __syncthreads();
    f16x8 fah[4][2], fal[4][2], fbh[4][2], fbl[4][2];
    #pragma unroll
    for (int i=0;i<4;i++)
      #pragma unroll
      for (int kb=0;kb<2;kb++){
        int ma = (wm*64 + i*16 + c_lane)*KSTRIDE + kb*32 + quad*8;
        int nb = (wn*64 + i*16 + c_lane)*KSTRIDE + kb*32 + quad*8;
        fah[i][kb] = *(const f16x8*)&ah[ma];
        fal[i][kb] = *(const f16x8*)&al[ma];
        fbh[i][kb] = *(const f16x8*)&bh[nb];
        fbl[i][kb] = *(const f16x8*)&bl[nb];
      }
    #pragma unroll
    for (int kb=0;kb<2;kb++)
      #pragma unroll
      for (int p=0;p<3;p++)
        #pragma unroll
        for (int mi=0;mi<4;mi++)
          #pragma unroll
          for (int ni=0;ni<4;ni++){
            f16x8 a = (p==2)? fal[mi][kb] : fah[mi][kb];
            f16x8 b = (p==1)? fbl[ni][kb] : fbh[ni][kb];
            acc[mi][ni] = __builtin_amdgcn_mfma_f32_16x16x32_f16(a, b, acc[mi][ni], 0,0,0);
          }
    __syncthreads();
  }

  // epilogue: n<512 -> qk16(hi)+qkl(lo); n>=512 -> v16
  #pragma unroll
  for (int mi=0;mi<4;mi++)
    #pragma unroll
    for (int ni=0;ni<4;ni++)
      #pragma unroll
      for (int r=0;r<4;r++){
        int n = n0 + wn*64 + ni*16 + c_lane;
        int tok = m0 + wm*64 + mi*16 + quad*4 + r;
        float val = acc[mi][ni][r];
        int b = tok >> 12, tp = tok & 4095;
        if (n < 512){
          int head = n >> 6, dd = n & 63;
          size_t idx = ((size_t)(b*NHEAD+head)*T_SZ + tp)*DH + dd;
          f16 hv = (f16)val;
          qk16[idx] = hv;
          qkl[idx]  = (f16)(val - (float)hv);
        } else {
          int j = n - 512, head = j >> 6, dd = j & 63;
          size_t idx = ((size_t)(b*NHEAD+head)*T_SZ + tp)*DH + dd;
          v16[idx] = (f16)val;
        }
      }
}

// ---------------- G2: fused round-combine + split-f16 GEMM  out = X @ Wout ----
// v6: back to the best-measured structure (R3: BM=128, A+B LDS-staged, 80us)
// + T14 issue-early prefetch. Evidence: R6 B-direct=90, R7 BM64+B-direct=110,
// R3 staged=80 -- occupancy was never the limiter; the per-phase serialized
// o-gather (HBM ~600cy) was. Prefetch (kc+1)'s o rows + lse into registers
// right AFTER the mid-phase barrier: loads stay in flight across frag-reads +
// MFMA and drain at the end-of-phase barrier's vmcnt(0). Combine order per
// element unchanged -> bit-identical output.
__global__ __launch_bounds__(256) void g_out(const float* __restrict__ lse,
    const f16* __restrict__ o_f16, const f16* __restrict__ Wth, const f16* __restrict__ Wtl,
    const float* __restrict__ bout, float* __restrict__ out)
{
  __shared__ f16 ah[128*KSTRIDE], al[128*KSTRIDE], bh[128*KSTRIDE], bl[128*KSTRIDE];
  int tid = threadIdx.x;
  int m0 = blockIdx.x*128, n0 = blockIdx.y*128;
  int w = tid >> 6, lane = tid & 63;
  int wm = w >> 1, wn = w & 1;
  int c_lane = lane & 15, quad = lane >> 4;
  const f16* Bh_base = Wth + (size_t)1024*512;   // Wout section
  const f16* Bl_base = Wtl + (size_t)1024*512;

  f32x4 acc[4][4];
  #pragma unroll
  for (int mi=0;mi<4;mi++)
    #pragma unroll
    for (int ni=0;ni<4;ni++) acc[mi][ni] = (f32x4){0.f,0.f,0.f,0.f};

  int sr = tid >> 1, sc = (tid & 1) * 32;
  int tok = m0 + sr;
  int tb = tok >> 12, tt = tok & 4095;

  // prefetch state for the A-side gather (o rows x 4 rounds + lse x 4)
  float pl0, pl1, pl2, pl3;
  f16x8 pr0[4], pr1[4], pr2[4], pr3[4];

  auto issueA = [&](int kc){
    size_t lbase = ((size_t)(tb*NHEAD + kc)*NHASH)*T_SZ + tt;
    pl0 = lse[lbase];
    pl1 = lse[lbase + T_SZ];
    pl2 = lse[lbase + 2*T_SZ];
    pl3 = lse[lbase + 3*T_SZ];
    const f16x8* r0 = (const f16x8*)(o_f16 + lbase*DH + sc);
    const f16x8* r1 = (const f16x8*)(o_f16 + (lbase + (size_t)T_SZ)*DH + sc);
    const f16x8* r2 = (const f16x8*)(o_f16 + (lbase + (size_t)2*T_SZ)*DH + sc);
    const f16x8* r3 = (const f16x8*)(o_f16 + (lbase + (size_t)3*T_SZ)*DH + sc);
    #pragma unroll
    for (int i=0;i<4;i++){ pr0[i]=r0[i]; pr1[i]=r1[i]; pr2[i]=r2[i]; pr3[i]=r3[i]; }
  };

  issueA(0);

  for (int kc=0; kc<8; kc++){
    int k0 = kc*64;
    {
      // ---- fused k5: combine 4 hash rounds (consumes prefetched regs) ----
      float M = fmaxf(fmaxf(pl0,pl1), fmaxf(pl2,pl3));
      float e0 = __expf(pl0-M), e1 = __expf(pl1-M), e2 = __expf(pl2-M), e3 = __expf(pl3-M);
      float inv = 1.0f/(e0+e1+e2+e3);
      float w0=e0*inv, w1=e1*inv, w2=e2*inv, w3=e3*inv;
      const f16x8* pbhp = (const f16x8*)(Bh_base + (size_t)(n0+sr)*512 + k0 + sc);
      const f16x8* pblp = (const f16x8*)(Bl_base + (size_t)(n0+sr)*512 + k0 + sc);
      f16x8* dah = (f16x8*)&ah[sr*KSTRIDE + sc];
      f16x8* dal = (f16x8*)&al[sr*KSTRIDE + sc];
      f16x8* dbh = (f16x8*)&bh[sr*KSTRIDE + sc];
      f16x8* dbl = (f16x8*)&bl[sr*KSTRIDE + sc];
      #pragma unroll
      for (int i=0;i<4;i++){
        f16x8 a = pr0[i], bb = pr1[i], cc = pr2[i], dd = pr3[i];
        f16x8 ho, lo;
        #pragma unroll
        for (int e=0;e<8;e++){
          float res = w0*(float)a[e] + w1*(float)bb[e] + w2*(float)cc[e] + w3*(float)dd[e];
          f16 hh = (f16)res;
          ho[e] = hh; lo[e] = (f16)(res - (float)hh);
        }
        dah[i] = ho; dal[i] = lo;
        dbh[i] = pbhp[i]; dbl[i] = pblp[i];
      }
    }
    __syncthreads();
    // issue next phase's gather NOW: in flight across frag reads + MFMA,
    // drains at the bottom barrier (after the compute it was hidden under).
    if (kc < 7) issueA(kc+1);
    f16x8 fah[4][2], fal[4][2], fbh[4][2], fbl[4][2];
    #pragma unroll
    for (int i=0;i<4;i++)
      #pragma unroll
      for (int kb=0;kb<2;kb++){
        int ma = (wm*64 + i*16 + c_lane)*KSTRIDE + kb*32 + quad*8;
        int nb = (wn*64 + i*16 + c_lane)*KSTRIDE + kb*32 + quad*8;
        fah[i][kb] = *(const f16x8*)&ah[ma];
        fal[i][kb] = *(const f16x8*)&al[ma];
        fbh[i][kb] = *(const f16x8*)&bh[nb];
        fbl[i][kb] = *(const f16x8*)&bl[nb];
      }
    #pragma unroll
    for (int kb=0;kb<2;kb++)
      #pragma unroll
      for (int p=0;p<3;p++)
        #pragma unroll
        for (int mi=0;mi<4;mi++)
          #pragma unroll
          for (int ni=0;ni<4;ni++){
            f16x8 a = (p==2)? fal[mi][kb] : fah[mi][kb];
            f16x8 b = (p==1)? fbl[ni][kb] : fbh[ni][kb];
            acc[mi][ni] = __builtin_amdgcn_mfma_f32_16x16x32_f16(a, b, acc[mi][ni], 0,0,0);
          }
    __syncthreads();
  }

  #pragma unroll
  for (int mi=0;mi<4;mi++)
    #pragma unroll
    for (int ni=0;ni<4;ni++){
      int n = n0 + wn*64 + ni*16 + c_lane;
      float bn = bout[n];
      #pragma unroll
      for (int r=0;r<4;r++){
        int tk2 = m0 + wm*64 + mi*16 + quad*4 + r;
        out[(size_t)tk2*512 + n] = acc[mi][ni][r] + bn;
      }
    }
}

// ---------------- K2: LSH hashing, rot-as-A MFMA + in-lane argmax epilogue ----
__global__ __launch_bounds__(256, 4) void k2_mfma(const f16* __restrict__ qkh,
    const f16* __restrict__ qkl, const f16* __restrict__ rotTh, const f16* __restrict__ rotTl,
    unsigned short* __restrict__ bucket,
    int* __restrict__ amb_list, int* __restrict__ amb_cnt)
{
  int tid = threadIdx.x;
  int w = tid >> 6, lane = tid & 63;
  int c_lane = lane & 15, quad = lane >> 4;
  int tok0 = (blockIdx.x*4 + w)*16;            // 16 tokens per wave
  size_t rowb = (size_t)(tok0 + c_lane)*64;

  // B fragments: token hi/lo (col = token = c_lane, k = kb*32 + quad*8 + e)
  f16x8 tbh[2], tbl[2];
  #pragma unroll
  for (int kb=0;kb<2;kb++){
    tbh[kb] = *(const f16x8*)&qkh[rowb + kb*32 + quad*8];
    tbl[kb] = *(const f16x8*)&qkl[rowb + kb*32 + quad*8];
  }

  f32x4 acc[8];
  #pragma unroll
  for (int mi=0;mi<8;mi++) acc[mi] = (f32x4){0.f,0.f,0.f,0.f};

  // A fragments: rot rows j = mi*16 + c_lane (L1-resident, 32KB total)
  #pragma unroll
  for (int mi=0;mi<8;mi++){
    int aoff = (mi*16 + c_lane)*64;
    #pragma unroll
    for (int kb=0;kb<2;kb++){
      f16x8 arh = *(const f16x8*)&rotTh[aoff + kb*32 + quad*8];
      f16x8 arl = *(const f16x8*)&rotTl[aoff + kb*32 + quad*8];
      acc[mi] = __builtin_amdgcn_mfma_f32_16x16x32_f16(arh, tbh[kb], acc[mi], 0,0,0);
      acc[mi] = __builtin_amdgcn_mfma_f32_16x16x32_f16(arl, tbh[kb], acc[mi], 0,0,0);
      acc[mi] = __builtin_amdgcn_mfma_f32_16x16x32_f16(arh, tbl[kb], acc[mi], 0,0,0);
    }
  }

  // lane (c_lane, quad) holds scores s[j] for token tok0+c_lane,
  // j = mi*16 + quad*4 + r  (mi = 0..7, r = 0..3)
  int tokg = tok0 + c_lane;
  int bhh = tokg >> 12, t = tokg & 4095;

  #pragma unroll
  for (int h=0; h<4; h++){
    float m1 = -1e30f, m2 = -1e30f, ssq = 0.f; int b1 = 0;
    #pragma unroll
    for (int u=0; u<8; u++){
      float v = acc[2*h + (u>>2)][u&3];
      int bidd = (u>>2)*16 + quad*4 + (u&3);   // within-hash index [0,32)
      ssq += v*v;
      if (v > m1){ m2=m1; m1=v; b1=bidd; } else if (v > m2) m2=v;
      float nv = -v;
      if (nv > m1){ m2=m1; m1=nv; b1=bidd+32; } else if (nv > m2) m2=nv;
    }
    // cross-quad reduce (lane bits 4,5)
    #pragma unroll
    for (int d2=16; d2<64; d2<<=1){
      float om1 = __shfl_xor(m1, d2);
      float om2 = __shfl_xor(m2, d2);
      int   ob1 = __shfl_xor(b1, d2);
      ssq += __shfl_xor(ssq, d2);
      if (om1 > m1){ m2 = fmaxf(m1, om2); m1 = om1; b1 = ob1; }
      else          { m2 = fmaxf(m2, om1); }
    }
    if (quad == 0){
      float rms = sqrtf(ssq * (1.0f/32.0f));
      if (m1 - m2 < AMB_TAU * rms){
        int idx = atomicAdd(amb_cnt, 1);
        amb_list[idx] = (bhh<<14) | (h<<12) | t;
      } else {
        bucket[((bhh*NHASH + h)<<12) + t] = (unsigned short)(b1 + (h<<6));
      }
    }
  }
}

// ---------------- K2fix: exact f64 recompute, 4-way d-parallel ----------------
__global__ __launch_bounds__(256) void k2_fix(const float* __restrict__ qin,
    const float* __restrict__ Wqk, const float* __restrict__ rot,
    const int* __restrict__ amb_list, const int* __restrict__ amb_cnt,
    unsigned short* __restrict__ bucket)
{
  __shared__ __align__(16) float qs[512];
  __shared__ double part[4][64];
  __shared__ double qk64[64];
  __shared__ double accs[32];
  int n = *amb_cnt;
  int tid = threadIdx.x;
  int j = tid & 63, chunk = tid >> 6;
  for (int it = blockIdx.x; it < n; it += gridDim.x){
    int gid = amb_list[it];
    int t = gid & (T_SZ-1);
    int h = (gid >> 12) & 3;
    int bh = gid >> 14;
    int b = bh >> 3, head = bh & 7;
    if (tid < 128)
      *(float4*)&qs[tid*4] = ((const float4*)(qin + ((size_t)b*T_SZ + t)*DMODEL))[tid];
    __syncthreads();
    const float* wcol = Wqk + head*64 + j;
    int d0 = chunk*128;
    double s = 0.0;
    #pragma unroll 16
    for (int d=0; d<128; d++)
      s += (double)qs[d0+d] * (double)wcol[(size_t)(d0+d)*512];
    part[chunk][j] = s;
    __syncthreads();
    if (tid < 64)
      qk64[tid] = ((part[0][tid] + part[1][tid]) + part[2][tid]) + part[3][tid];
    __syncthreads();
    if (tid < 32){
      double a = 0.0;
      #pragma unroll 16
      for (int f=0; f<64; f++)
        a += qk64[f] * (double)rot[f*(NHASH*32) + h*32 + tid];
      accs[tid] = a;
    }
    __syncthreads();
    if (tid == 0){
      double best = accs[0]; int bk = 0;
      for (int k=1;k<64;k++){
        double vv = (k<32)? accs[k] : -accs[k-32];
        if (vv > best){ best = vv; bk = k; }
      }
      bucket[((bh*NHASH + h)<<12) + t] = (unsigned short)(bk + (h<<6));
    }
    __syncthreads();
  }
}

// ---------------- K3: LDS histogram from bucket + exclusive prefix scan -------
__global__ __launch_bounds__(256) void k3_scan(const unsigned short* __restrict__ bucket,
    int* __restrict__ starts){
  __shared__ int s[256];
  int bh = blockIdx.x, tid = threadIdx.x;
  s[tid] = 0;
  __syncthreads();
  const u16x8* b8 = (const u16x8*)(bucket + ((size_t)bh*NHASH << 12));
  for (int i = tid; i < 2048; i += 256){   // 16384 u16 = 2048 x u16x8
    u16x8 x = b8[i];
    #pragma unroll
    for (int e=0;e<8;e++) atomicAdd(&s[x[e]], 1);
  }
  __syncthreads();
  int v = s[tid];
  __syncthreads();
  for (int off=1; off<256; off<<=1){
    int a = (tid >= off) ? s[tid-off] : 0;
    __syncthreads();
    s[tid] += a;
    __syncthreads();
  }
  starts[bh*256 + tid] = s[tid] - v;
}

// ---------------- K3b: stable counting-sort scatter ----------------
__global__ __launch_bounds__(64) void k3b_scatter(const unsigned short* __restrict__ bucket,
    const int* __restrict__ starts, int* __restrict__ st)
{
  int blk = blockIdx.x;
  int bh = blk >> 8; int g = blk & 255; int h = g >> 6;
  int lane = threadIdx.x;
  const unsigned short* brow = bucket + ((bh*NHASH + h)<<12);
  int base = starts[bh*NBUCK + g];
  for (int step=0; step<64; step++){
    int t = step*64 + lane;
    bool pred = (brow[t] == (unsigned short)g);
    unsigned long long mask = __ballot(pred);
    if (pred){
      int off = __popcll(mask & ((1ull<<lane) - 1ull));
      st[bh*TOT + base + off] = t;
    }
    base += __popcll(mask);
  }
}

// ---------------- K4: MFMA chunked LSH attention ------------------------------
// 4 cooperative waves per chunk (wave w owns query sub-tile mi=w).
// 36864B LDS -> 4 blocks/CU at 256 thr = 16 waves/CU. XCD-aware swizzle.
__global__ __launch_bounds__(256, 4) void k4_attn(const f16* __restrict__ qk16,
    const f16* __restrict__ v16, const int* __restrict__ st,
    float* __restrict__ lse_out, f16* __restrict__ o_out)
{
  __shared__ __align__(16) char smem[36864];
  f16*   k_lds   = (f16*)smem;                 // 128 x KSTRIDE (alias p_lds)
  f16*   p_lds   = (f16*)smem;                 // 64 x PSTRIDE
  f16*   vT      = (f16*)(smem + 18432);       // 64 x PSTRIDE (d-major)
  float* invnorm = (float*)(smem + 35840);
  int*   kv_t    = (int*)(smem + 36352);

  int bid = blockIdx.x;
  int swz = (bid & 7) * 1024 + (bid >> 3);     // bijective: 8192 = 8*1024
  int bh = swz >> 8; int c = swz & 255;
  int h = c >> 6; int cp = (c + 255) & 255;
  int tid = threadIdx.x;
  int w = tid >> 6, lane = tid & 63;
  int c_lane = lane & 15, quad = lane >> 4;
  const int* strow = st + bh*TOT;

  // ---- load phase: threads 0..127, one full K/V row each
  if (tid < 128){
    int row = tid;
    int slot = (row < 64) ? (c*64 + row) : (cp*64 + row - 64);
    int t = strow[slot];
    kv_t[row] = t;
    const f16x8* kr = (const f16x8*)(qk16 + ((size_t)bh*T_SZ + t)*DH);
    const f16x8* vr = (const f16x8*)(v16  + ((size_t)bh*T_SZ + t)*DH);
    f16x8 kv[8], vv[8];
    float ss = 0.f;
    #pragma unroll
    for (int i=0;i<8;i++){
      f16x8 x = kr[i]; kv[i] = x;
      vv[i] = vr[i];
      #pragma unroll
      for (int e=0;e<8;e++){ float f = (float)x[e]; ss += f*f; }
    }
    invnorm[row] = 1.0f / fmaxf(sqrtf(ss), 1e-12f);
    f16x8* kd = (f16x8*)&k_lds[row*KSTRIDE];
    #pragma unroll
    for (int i=0;i<8;i++) kd[i] = kv[i];
    #pragma unroll
    for (int i=0;i<8;i++){
      #pragma unroll
      for (int e=0;e<8;e++) vT[(i*8+e)*PSTRIDE + row] = vv[i][e];
    }
  }
  __syncthreads();

  // ---- QK^T: wave w computes query sub-tile mi = w ----
  int mi = w;
  f16x8 aq[2];
  #pragma unroll
  for (int kb=0;kb<2;kb++)
    aq[kb] = *(const f16x8*)&k_lds[(mi*16 + c_lane)*KSTRIDE + kb*32 + quad*8];

  f32x4 accS[8];
  #pragma unroll
  for (int ni=0;ni<8;ni++) accS[ni] = (f32x4){0.f,0.f,0.f,0.f};

  #pragma unroll
  for (int ni=0;ni<8;ni++){
    int rowb = ni*16 + c_lane;
    f16 sc = (f16)invnorm[rowb];
    f16x8 b0 = *(const f16x8*)&k_lds[rowb*KSTRIDE + 0*32 + quad*8];
    f16x8 b1 = *(const f16x8*)&k_lds[rowb*KSTRIDE + 1*32 + quad*8];
    b0 *= sc; b1 *= sc;
    accS[ni] = __builtin_amdgcn_mfma_f32_16x16x32_f16(aq[0], b0, accS[ni], 0,0,0);
    accS[ni] = __builtin_amdgcn_mfma_f32_16x16x32_f16(aq[1], b1, accS[ni], 0,0,0);
  }

  int tq[4];
  #pragma unroll
  for (int r=0;r<4;r++) tq[r] = kv_t[mi*16 + quad*4 + r];
  int tk[8];
  #pragma unroll
  for (int ni=0;ni<8;ni++) tk[ni] = kv_t[ni*16 + c_lane];

  float mrow[4], lrow[4];
  #pragma unroll
  for (int r=0;r<4;r++){
    float mx = -1e30f;
    #pragma unroll
    for (int ni=0;ni<8;ni++){
      float s = accS[ni][r] * 0.125f;
      if (tk[ni] == tq[r]) s = -50000.0f;
      accS[ni][r] = s;
      mx = fmaxf(mx, s);
    }
    mx = fmaxf(mx, __shfl_xor(mx, 1));
    mx = fmaxf(mx, __shfl_xor(mx, 2));
    mx = fmaxf(mx, __shfl_xor(mx, 4));
    mx = fmaxf(mx, __shfl_xor(mx, 8));
    mrow[r] = mx;
    float ls = 0.f;
    #pragma unroll
    for (int ni=0;ni<8;ni++){
      float e = __expf(accS[ni][r] - mx);
      accS[ni][r] = e;
      ls += e;
    }
    ls += __shfl_xor(ls, 1);
    ls += __shfl_xor(ls, 2);
    ls += __shfl_xor(ls, 4);
    ls += __shfl_xor(ls, 8);
    lrow[r] = ls;
  }

  // all waves done reading k_lds (aliased with p_lds) before any P write
  __syncthreads();

  #pragma unroll
  for (int ni=0;ni<8;ni++)
    #pragma unroll
    for (int r=0;r<4;r++)
      p_lds[(mi*16 + quad*4 + r)*PSTRIDE + ni*16 + c_lane] = (f16)accS[ni][r];

  // wave reads only its own P rows -> no cross-wave barrier needed
  f16x8 pa[4];
  #pragma unroll
  for (int kb=0;kb<4;kb++)
    pa[kb] = *(const f16x8*)&p_lds[(mi*16 + c_lane)*PSTRIDE + kb*32 + quad*8];

  size_t rowbase = (size_t)(bh*NHASH + h)*T_SZ;
  #pragma unroll
  for (int ni2=0;ni2<4;ni2++){
    f16x8 bv[4];
    #pragma unroll
    for (int kb=0;kb<4;kb++)
      bv[kb] = *(const f16x8*)&vT[(ni2*16 + c_lane)*PSTRIDE + kb*32 + quad*8];
    f32x4 accO = (f32x4){0.f,0.f,0.f,0.f};
    #pragma unroll
    for (int kb=0;kb<4;kb++)
      accO = __builtin_amdgcn_mfma_f32_16x16x32_f16(pa[kb], bv[kb], accO, 0,0,0);
    #pragma unroll
    for (int r=0;r<4;r++){
      float invl = 1.0f / lrow[r];
      f16* orow = o_out + (rowbase + tq[r])*DH;
      orow[ni2*16 + c_lane] = (f16)(accO[r] * invl);
    }
  }
  #pragma unroll
  for (int r=0;r<4;r++){
    if (c_lane == 0)
      lse_out[rowbase + tq[r]] = mrow[r] + logf(lrow[r]);
  }
}

// ---------------- launch ----------------
extern "C" void kernel_launch(void* const* d_in, const int* in_sizes, int n_in,
                              void* d_out, int out_size, void* d_ws, size_t ws_size,
                              hipStream_t stream) {
  const float* queries = (const float*)d_in[0];
  const float* Wqk     = (const float*)d_in[3];
  const float* Wv      = (const float*)d_in[4];
  const float* Wout    = (const float*)d_in[5];
  const float* bout    = (const float*)d_in[6];
  const float* rot     = (const float*)d_in[7];
  float* out = (float*)d_out;

  const size_t SZ_F16  = (size_t)BH*T_SZ*DH*2;        // 16 MB
  const size_t SZ_WT   = (size_t)1536*512*2;          // 1.5 MB
  const size_t SZ_ROT  = (size_t)128*64*2;            // 16 KB
  const size_t SZ_O    = (size_t)BH*NHASH*T_SZ*DH*2;  // 64 MB
  const size_t OFS_X      = 0;
  const size_t OFS_AH     = OFS_X    + 2*SZ_F16;
  const size_t OFS_AL     = OFS_AH   + SZ_F16;
  const size_t OFS_QK16   = OFS_AL   + SZ_F16;
  const size_t OFS_V16    = OFS_QK16 + SZ_F16;
  const size_t OFS_WTH    = OFS_V16  + SZ_F16;
  const size_t OFS_WTL    = OFS_WTH  + SZ_WT;
  const size_t OFS_ROTH   = OFS_WTL  + SZ_WT;
  const size_t OFS_ROTL   = OFS_ROTH + SZ_ROT;
  const size_t OFS_O      = OFS_ROTL + SZ_ROT;
  const size_t OFS_BUCKET = OFS_O    + SZ_O;
  const size_t OFS_HIST   = OFS_BUCKET + (size_t)BH*NHASH*T_SZ*2;
  const size_t OFS_STARTS = OFS_HIST   + (size_t)BH*NBUCK*4;
  const size_t OFS_ST     = OFS_STARTS + (size_t)BH*NBUCK*4;
  const size_t OFS_LSE    = OFS_ST     + (size_t)BH*TOT*4;
  const size_t OFS_AMB    = OFS_LSE    + (size_t)BH*NHASH*T_SZ*4;
  const size_t OFS_CNT    = OFS_AMB    + (size_t)BH*NHASH*T_SZ*4;
  const size_t WS_NEEDED  = OFS_CNT    + 256;
  if (ws_size < WS_NEEDED) return;

  char* ws = (char*)d_ws;
  f16*      qkl    = (f16*)(ws + OFS_X);               // lo split of qk (g_qkv/k2)
  f16*      Ah     = (f16*)(ws + OFS_AH);
  f16*      Al     = (f16*)(ws + OFS_AL);
  f16*      qk16   = (f16*)(ws + OFS_QK16);
  f16*      v16    = (f16*)(ws + OFS_V16);
  f16*      Wth    = (f16*)(ws + OFS_WTH);
  f16*      Wtl    = (f16*)(ws + OFS_WTL);
  f16*      rotTh  = (f16*)(ws + OFS_ROTH);
  f16*      rotTl  = (f16*)(ws + OFS_ROTL);
  f16*      o_f16  = (f16*)(ws + OFS_O);
  unsigned short* bucket = (unsigned short*)(ws + OFS_BUCKET);
  int*      starts = (int*)(ws + OFS_STARTS);
  int*      st     = (int*)(ws + OFS_ST);
  float*    lse    = (float*)(ws + OFS_LSE);
  int*      amb    = (int*)(ws + OFS_AMB);
  int*      cnt    = (int*)(ws + OFS_CNT);

  kprep     <<<7200, 256, 0, stream>>>(Wqk, Wv, Wout, Wth, Wtl, rot, rotTh, rotTl,
                                       queries, Ah, Al, cnt);
  g_qkv     <<<dim3(M_TOK/128, 8), 256, 0, stream>>>(Ah, Al, Wth, Wtl, qk16, qkl, v16);
  k2_mfma   <<<(BH*T_SZ)/64, 256, 0, stream>>>(qk16, qkl, rotTh, rotTl, bucket, amb, cnt);
  k2_fix    <<<2048, 256, 0, stream>>>(queries, Wqk, rot, amb, cnt, bucket);
  k3_scan   <<<BH, 256, 0, stream>>>(bucket, starts);
  k3b_scatter<<<BH*NBUCK, 64, 0, stream>>>(bucket, starts, st);
  k4_attn   <<<BH*256, 256, 0, stream>>>(qk16, v16, st, lse, o_f16);
  g_out     <<<dim3(M_TOK/128, 4), 256, 0, stream>>>(lse, o_f16, Wth, Wtl, bout, out);
}

// Round 9
// 424.963 us; speedup vs baseline: 1.1137x; 1.0210x over previous
//
#include <hip/hip_runtime.h>

typedef unsigned int uint32;
typedef _Float16 f16;
typedef _Float16 f16x8 __attribute__((ext_vector_type(8)));
typedef float f32x4 __attribute__((ext_vector_type(4)));
typedef unsigned short u16x8 __attribute__((ext_vector_type(8)));

#define B_SZ 4
#define T_SZ 4096
#define DMODEL 512
#define NHEAD 8
#define DH 64
#define NHASH 4
#define BH (B_SZ*NHEAD)      // 32
#define NBUCK 256
#define TOT (NHASH*T_SZ)     // 16384
#define M_TOK (B_SZ*T_SZ)    // 16384

#define KSTRIDE 72           // f16 elems per LDS row (128B data + 16B pad)
#define PSTRIDE 136

// split-f16 MFMA hash-score worst-case error ~4e-5*rms; keep >=35x margin.
#define AMB_TAU 1.5e-3f

// ---------------- KPREP: fused {zero cnt, W split, rot split, query split} ---
// blockIdx ranges: [0,3072) = kw_t, [3072,3104) = kr_t, [3104,7200) = k1a.
__global__ __launch_bounds__(256) void kprep(
    const float* __restrict__ Wqk, const float* __restrict__ Wv,
    const float* __restrict__ Wout, f16* __restrict__ Wth, f16* __restrict__ Wtl,
    const float* __restrict__ rot, f16* __restrict__ rotTh, f16* __restrict__ rotTl,
    const float* __restrict__ qin, f16* __restrict__ Ah, f16* __restrict__ Al,
    int* __restrict__ amb_cnt)
{
  int bx = blockIdx.x;
  if (bx == 0 && threadIdx.x == 0) *amb_cnt = 0;
  if (bx < 3072){
    int gid = bx*256 + threadIdx.x;
    int n = gid >> 9, k = gid & 511;
    int sel = n >> 9, col = n & 511;
    const float* src = (sel==0)? Wqk : (sel==1)? Wv : Wout;
    float v = src[(size_t)k*512 + col];
    f16 h = (f16)v;
    Wth[gid] = h;
    Wtl[gid] = (f16)(v - (float)h);
  } else if (bx < 3104){
    int gid = (bx - 3072)*256 + threadIdx.x;   // [0, 128*64)
    int n = gid >> 6, dd = gid & 63;
    float v = rot[dd*128 + n];
    f16 h = (f16)v;
    rotTh[gid] = h;
    rotTl[gid] = (f16)(v - (float)h);
  } else {
    size_t gid = (size_t)(bx - 3104)*256 + threadIdx.x;
    const float4* src = (const float4*)(qin) + gid*2;
    float4 x0 = src[0], x1 = src[1];
    float v[8] = {x0.x,x0.y,x0.z,x0.w, x1.x,x1.y,x1.z,x1.w};
    f16x8 h, l;
    #pragma unroll
    for (int e=0;e<8;e++){ f16 hh=(f16)v[e]; h[e]=hh; l[e]=(f16)(v[e]-(float)hh); }
    ((f16x8*)Ah)[gid] = h;
    ((f16x8*)Al)[gid] = l;
  }
}

// ---------------- G1: split-f16 MFMA GEMM  qk|v = queries @ [Wqk|Wv] ---------
// v2: T14 issue-early prefetch (same structure that took g_out 90->~65 in R8).
// Per phase the global loads for (kc+1) are issued right after the top
// barrier, stay in flight across frag-reads + 48 MFMAs, and drain at the
// bottom barrier's vmcnt(0). MFMA order untouched -> bit-identical.
__global__ __launch_bounds__(256) void g_qkv(const f16* __restrict__ Ah,
    const f16* __restrict__ Al, const f16* __restrict__ Wth, const f16* __restrict__ Wtl,
    f16* __restrict__ qk16, f16* __restrict__ qkl, f16* __restrict__ v16)
{
  __shared__ f16 ah[128*KSTRIDE], al[128*KSTRIDE], bh[128*KSTRIDE], bl[128*KSTRIDE];
  int tid = threadIdx.x;
  int m0 = blockIdx.x*128, n0 = blockIdx.y*128;
  int w = tid >> 6, lane = tid & 63;
  int wm = w >> 1, wn = w & 1;
  int c_lane = lane & 15, quad = lane >> 4;

  f32x4 acc[4][4];
  #pragma unroll
  for (int mi=0;mi<4;mi++)
    #pragma unroll
    for (int ni=0;ni<4;ni++) acc[mi][ni] = (f32x4){0.f,0.f,0.f,0.f};

  int sr = tid >> 1, sc = (tid & 1) * 32;

  // prefetch registers for the next tile (A hi/lo, B hi/lo)
  f16x8 pA[4], pAl[4], pB[4], pBl[4];
  auto issue = [&](int kc){
    int k0 = kc*64;
    const f16x8* pah = (const f16x8*)(Ah + (size_t)(m0+sr)*512 + k0 + sc);
    const f16x8* pal = (const f16x8*)(Al + (size_t)(m0+sr)*512 + k0 + sc);
    const f16x8* pbh = (const f16x8*)(Wth + (size_t)(n0+sr)*512 + k0 + sc);
    const f16x8* pbl = (const f16x8*)(Wtl + (size_t)(n0+sr)*512 + k0 + sc);
    #pragma unroll
    for (int i=0;i<4;i++){ pA[i]=pah[i]; pAl[i]=pal[i]; pB[i]=pbh[i]; pBl[i]=pbl[i]; }
  };

  issue(0);

  for (int kc=0; kc<8; kc++){
    {
      f16x8* dah = (f16x8*)&ah[sr*KSTRIDE + sc];
      f16x8* dal = (f16x8*)&al[sr*KSTRIDE + sc];
      f16x8* dbh = (f16x8*)&bh[sr*KSTRIDE + sc];
      f16x8* dbl = (f16x8*)&bl[sr*KSTRIDE + sc];
      #pragma unroll
      for (int i=0;i<4;i++){ dah[i]=pA[i]; dal[i]=pAl[i]; dbh[i]=pB[i]; dbl[i]=pBl[i]; }
    }
    __syncthreads();
    // issue next tile's loads NOW: hidden under frag reads + MFMA
    if (kc < 7) issue(kc+1);
    f16x8 fah[4][2], fal[4][2], fbh[4][2], fbl[4][2];
    #pragma unroll
    for (int i=0;i<4;i++)
      #pragma unroll
      for (int kb=0;kb<2;kb++){
        int ma = (wm*64 + i*16 + c_lane)*KSTRIDE + kb*32 + quad*8;
        int nb = (wn*64 + i*16 + c_lane)*KSTRIDE + kb*32 + quad*8;
        fah[i][kb] = *(const f16x8*)&ah[ma];
        fal[i][kb] = *(const f16x8*)&al[ma];
        fbh[i][kb] = *(const f16x8*)&bh[nb];
        fbl[i][kb] = *(const f16x8*)&bl[nb];
      }
    #pragma unroll
    for (int kb=0;kb<2;kb++)
      #pragma unroll
      for (int p=0;p<3;p++)
        #pragma unroll
        for (int mi=0;mi<4;mi++)
          #pragma unroll
          for (int ni=0;ni<4;ni++){
            f16x8 a = (p==2)? fal[mi][kb] : fah[mi][kb];
            f16x8 b = (p==1)? fbl[ni][kb] : fbh[ni][kb];
            acc[mi][ni] = __builtin_amdgcn_mfma_f32_16x16x32_f16(a, b, acc[mi][ni], 0,0,0);
          }
    __syncthreads();
  }

  // epilogue: n<512 -> qk16(hi)+qkl(lo); n>=512 -> v16
  #pragma unroll
  for (int mi=0;mi<4;mi++)
    #pragma unroll
    for (int ni=0;ni<4;ni++)
      #pragma unroll
      for (int r=0;r<4;r++){
        int n = n0 + wn*64 + ni*16 + c_lane;
        int tok = m0 + wm*64 + mi*16 + quad*4 + r;
        float val = acc[mi][ni][r];
        int b = tok >> 12, tp = tok & 4095;
        if (n < 512){
          int head = n >> 6, dd = n & 63;
          size_t idx = ((size_t)(b*NHEAD+head)*T_SZ + tp)*DH + dd;
          f16 hv = (f16)val;
          qk16[idx] = hv;
          qkl[idx]  = (f16)(val - (float)hv);
        } else {
          int j = n - 512, head = j >> 6, dd = j & 63;
          size_t idx = ((size_t)(b*NHEAD+head)*T_SZ + tp)*DH + dd;
          v16[idx] = (f16)val;
        }
      }
}

// ---------------- G2: fused round-combine + split-f16 GEMM  out = X @ Wout ----
// R3 structure (BM=128, A+B LDS-staged) + T14 issue-early prefetch (R8 win).
__global__ __launch_bounds__(256) void g_out(const float* __restrict__ lse,
    const f16* __restrict__ o_f16, const f16* __restrict__ Wth, const f16* __restrict__ Wtl,
    const float* __restrict__ bout, float* __restrict__ out)
{
  __shared__ f16 ah[128*KSTRIDE], al[128*KSTRIDE], bh[128*KSTRIDE], bl[128*KSTRIDE];
  int tid = threadIdx.x;
  int m0 = blockIdx.x*128, n0 = blockIdx.y*128;
  int w = tid >> 6, lane = tid & 63;
  int wm = w >> 1, wn = w & 1;
  int c_lane = lane & 15, quad = lane >> 4;
  const f16* Bh_base = Wth + (size_t)1024*512;   // Wout section
  const f16* Bl_base = Wtl + (size_t)1024*512;

  f32x4 acc[4][4];
  #pragma unroll
  for (int mi=0;mi<4;mi++)
    #pragma unroll
    for (int ni=0;ni<4;ni++) acc[mi][ni] = (f32x4){0.f,0.f,0.f,0.f};

  int sr = tid >> 1, sc = (tid & 1) * 32;
  int tok = m0 + sr;
  int tb = tok >> 12, tt = tok & 4095;

  // prefetch state for the A-side gather (o rows x 4 rounds + lse x 4)
  float pl0, pl1, pl2, pl3;
  f16x8 pr0[4], pr1[4], pr2[4], pr3[4];

  auto issueA = [&](int kc){
    size_t lbase = ((size_t)(tb*NHEAD + kc)*NHASH)*T_SZ + tt;
    pl0 = lse[lbase];
    pl1 = lse[lbase + T_SZ];
    pl2 = lse[lbase + 2*T_SZ];
    pl3 = lse[lbase + 3*T_SZ];
    const f16x8* r0 = (const f16x8*)(o_f16 + lbase*DH + sc);
    const f16x8* r1 = (const f16x8*)(o_f16 + (lbase + (size_t)T_SZ)*DH + sc);
    const f16x8* r2 = (const f16x8*)(o_f16 + (lbase + (size_t)2*T_SZ)*DH + sc);
    const f16x8* r3 = (const f16x8*)(o_f16 + (lbase + (size_t)3*T_SZ)*DH + sc);
    #pragma unroll
    for (int i=0;i<4;i++){ pr0[i]=r0[i]; pr1[i]=r1[i]; pr2[i]=r2[i]; pr3[i]=r3[i]; }
  };

  issueA(0);

  for (int kc=0; kc<8; kc++){
    int k0 = kc*64;
    {
      // ---- fused k5: combine 4 hash rounds (consumes prefetched regs) ----
      float M = fmaxf(fmaxf(pl0,pl1), fmaxf(pl2,pl3));
      float e0 = __expf(pl0-M), e1 = __expf(pl1-M), e2 = __expf(pl2-M), e3 = __expf(pl3-M);
      float inv = 1.0f/(e0+e1+e2+e3);
      float w0=e0*inv, w1=e1*inv, w2=e2*inv, w3=e3*inv;
      const f16x8* pbhp = (const f16x8*)(Bh_base + (size_t)(n0+sr)*512 + k0 + sc);
      const f16x8* pblp = (const f16x8*)(Bl_base + (size_t)(n0+sr)*512 + k0 + sc);
      f16x8* dah = (f16x8*)&ah[sr*KSTRIDE + sc];
      f16x8* dal = (f16x8*)&al[sr*KSTRIDE + sc];
      f16x8* dbh = (f16x8*)&bh[sr*KSTRIDE + sc];
      f16x8* dbl = (f16x8*)&bl[sr*KSTRIDE + sc];
      #pragma unroll
      for (int i=0;i<4;i++){
        f16x8 a = pr0[i], bb = pr1[i], cc = pr2[i], dd = pr3[i];
        f16x8 ho, lo;
        #pragma unroll
        for (int e=0;e<8;e++){
          float res = w0*(float)a[e] + w1*(float)bb[e] + w2*(float)cc[e] + w3*(float)dd[e];
          f16 hh = (f16)res;
          ho[e] = hh; lo[e] = (f16)(res - (float)hh);
        }
        dah[i] = ho; dal[i] = lo;
        dbh[i] = pbhp[i]; dbl[i] = pblp[i];
      }
    }
    __syncthreads();
    // issue next phase's gather NOW: in flight across frag reads + MFMA,
    // drains at the bottom barrier (after the compute it was hidden under).
    if (kc < 7) issueA(kc+1);
    f16x8 fah[4][2], fal[4][2], fbh[4][2], fbl[4][2];
    #pragma unroll
    for (int i=0;i<4;i++)
      #pragma unroll
      for (int kb=0;kb<2;kb++){
        int ma = (wm*64 + i*16 + c_lane)*KSTRIDE + kb*32 + quad*8;
        int nb = (wn*64 + i*16 + c_lane)*KSTRIDE + kb*32 + quad*8;
        fah[i][kb] = *(const f16x8*)&ah[ma];
        fal[i][kb] = *(const f16x8*)&al[ma];
        fbh[i][kb] = *(const f16x8*)&bh[nb];
        fbl[i][kb] = *(const f16x8*)&bl[nb];
      }
    #pragma unroll
    for (int kb=0;kb<2;kb++)
      #pragma unroll
      for (int p=0;p<3;p++)
        #pragma unroll
        for (int mi=0;mi<4;mi++)
          #pragma unroll
          for (int ni=0;ni<4;ni++){
            f16x8 a = (p==2)? fal[mi][kb] : fah[mi][kb];
            f16x8 b = (p==1)? fbl[ni][kb] : fbh[ni][kb];
            acc[mi][ni] = __builtin_amdgcn_mfma_f32_16x16x32_f16(a, b, acc[mi][ni], 0,0,0);
          }
    __syncthreads();
  }

  #pragma unroll
  for (int mi=0;mi<4;mi++)
    #pragma unroll
    for (int ni=0;ni<4;ni++){
      int n = n0 + wn*64 + ni*16 + c_lane;
      float bn = bout[n];
      #pragma unroll
      for (int r=0;r<4;r++){
        int tk2 = m0 + wm*64 + mi*16 + quad*4 + r;
        out[(size_t)tk2*512 + n] = acc[mi][ni][r] + bn;
      }
    }
}

// ---------------- K2: LSH hashing, rot-as-A MFMA + in-lane argmax epilogue ----
__global__ __launch_bounds__(256, 4) void k2_mfma(const f16* __restrict__ qkh,
    const f16* __restrict__ qkl, const f16* __restrict__ rotTh, const f16* __restrict__ rotTl,
    unsigned short* __restrict__ bucket,
    int* __restrict__ amb_list, int* __restrict__ amb_cnt)
{
  int tid = threadIdx.x;
  int w = tid >> 6, lane = tid & 63;
  int c_lane = lane & 15, quad = lane >> 4;
  int tok0 = (blockIdx.x*4 + w)*16;            // 16 tokens per wave
  size_t rowb = (size_t)(tok0 + c_lane)*64;

  // B fragments: token hi/lo (col = token = c_lane, k = kb*32 + quad*8 + e)
  f16x8 tbh[2], tbl[2];
  #pragma unroll
  for (int kb=0;kb<2;kb++){
    tbh[kb] = *(const f16x8*)&qkh[rowb + kb*32 + quad*8];
    tbl[kb] = *(const f16x8*)&qkl[rowb + kb*32 + quad*8];
  }

  f32x4 acc[8];
  #pragma unroll
  for (int mi=0;mi<8;mi++) acc[mi] = (f32x4){0.f,0.f,0.f,0.f};

  // A fragments: rot rows j = mi*16 + c_lane (L1-resident, 32KB total)
  #pragma unroll
  for (int mi=0;mi<8;mi++){
    int aoff = (mi*16 + c_lane)*64;
    #pragma unroll
    for (int kb=0;kb<2;kb++){
      f16x8 arh = *(const f16x8*)&rotTh[aoff + kb*32 + quad*8];
      f16x8 arl = *(const f16x8*)&rotTl[aoff + kb*32 + quad*8];
      acc[mi] = __builtin_amdgcn_mfma_f32_16x16x32_f16(arh, tbh[kb], acc[mi], 0,0,0);
      acc[mi] = __builtin_amdgcn_mfma_f32_16x16x32_f16(arl, tbh[kb], acc[mi], 0,0,0);
      acc[mi] = __builtin_amdgcn_mfma_f32_16x16x32_f16(arh, tbl[kb], acc[mi], 0,0,0);
    }
  }

  // lane (c_lane, quad) holds scores s[j] for token tok0+c_lane,
  // j = mi*16 + quad*4 + r  (mi = 0..7, r = 0..3)
  int tokg = tok0 + c_lane;
  int bhh = tokg >> 12, t = tokg & 4095;

  #pragma unroll
  for (int h=0; h<4; h++){
    float m1 = -1e30f, m2 = -1e30f, ssq = 0.f; int b1 = 0;
    #pragma unroll
    for (int u=0; u<8; u++){
      float v = acc[2*h + (u>>2)][u&3];
      int bidd = (u>>2)*16 + quad*4 + (u&3);   // within-hash index [0,32)
      ssq += v*v;
      if (v > m1){ m2=m1; m1=v; b1=bidd; } else if (v > m2) m2=v;
      float nv = -v;
      if (nv > m1){ m2=m1; m1=nv; b1=bidd+32; } else if (nv > m2) m2=nv;
    }
    // cross-quad reduce (lane bits 4,5)
    #pragma unroll
    for (int d2=16; d2<64; d2<<=1){
      float om1 = __shfl_xor(m1, d2);
      float om2 = __shfl_xor(m2, d2);
      int   ob1 = __shfl_xor(b1, d2);
      ssq += __shfl_xor(ssq, d2);
      if (om1 > m1){ m2 = fmaxf(m1, om2); m1 = om1; b1 = ob1; }
      else          { m2 = fmaxf(m2, om1); }
    }
    if (quad == 0){
      float rms = sqrtf(ssq * (1.0f/32.0f));
      if (m1 - m2 < AMB_TAU * rms){
        int idx = atomicAdd(amb_cnt, 1);
        amb_list[idx] = (bhh<<14) | (h<<12) | t;
      } else {
        bucket[((bhh*NHASH + h)<<12) + t] = (unsigned short)(b1 + (h<<6));
      }
    }
  }
}

// ---------------- K2fix: exact f64 recompute, 4-way d-parallel ----------------
__global__ __launch_bounds__(256) void k2_fix(const float* __restrict__ qin,
    const float* __restrict__ Wqk, const float* __restrict__ rot,
    const int* __restrict__ amb_list, const int* __restrict__ amb_cnt,
    unsigned short* __restrict__ bucket)
{
  __shared__ __align__(16) float qs[512];
  __shared__ double part[4][64];
  __shared__ double qk64[64];
  __shared__ double accs[32];
  int n = *amb_cnt;
  int tid = threadIdx.x;
  int j = tid & 63, chunk = tid >> 6;
  for (int it = blockIdx.x; it < n; it += gridDim.x){
    int gid = amb_list[it];
    int t = gid & (T_SZ-1);
    int h = (gid >> 12) & 3;
    int bh = gid >> 14;
    int b = bh >> 3, head = bh & 7;
    if (tid < 128)
      *(float4*)&qs[tid*4] = ((const float4*)(qin + ((size_t)b*T_SZ + t)*DMODEL))[tid];
    __syncthreads();
    const float* wcol = Wqk + head*64 + j;
    int d0 = chunk*128;
    double s = 0.0;
    #pragma unroll 16
    for (int d=0; d<128; d++)
      s += (double)qs[d0+d] * (double)wcol[(size_t)(d0+d)*512];
    part[chunk][j] = s;
    __syncthreads();
    if (tid < 64)
      qk64[tid] = ((part[0][tid] + part[1][tid]) + part[2][tid]) + part[3][tid];
    __syncthreads();
    if (tid < 32){
      double a = 0.0;
      #pragma unroll 16
      for (int f=0; f<64; f++)
        a += qk64[f] * (double)rot[f*(NHASH*32) + h*32 + tid];
      accs[tid] = a;
    }
    __syncthreads();
    if (tid == 0){
      double best = accs[0]; int bk = 0;
      for (int k=1;k<64;k++){
        double vv = (k<32)? accs[k] : -accs[k-32];
        if (vv > best){ best = vv; bk = k; }
      }
      bucket[((bh*NHASH + h)<<12) + t] = (unsigned short)(bk + (h<<6));
    }
    __syncthreads();
  }
}

// ---------------- K3: LDS histogram from bucket + exclusive prefix scan -------
__global__ __launch_bounds__(256) void k3_scan(const unsigned short* __restrict__ bucket,
    int* __restrict__ starts){
  __shared__ int s[256];
  int bh = blockIdx.x, tid = threadIdx.x;
  s[tid] = 0;
  __syncthreads();
  const u16x8* b8 = (const u16x8*)(bucket + ((size_t)bh*NHASH << 12));
  for (int i = tid; i < 2048; i += 256){   // 16384 u16 = 2048 x u16x8
    u16x8 x = b8[i];
    #pragma unroll
    for (int e=0;e<8;e++) atomicAdd(&s[x[e]], 1);
  }
  __syncthreads();
  int v = s[tid];
  __syncthreads();
  for (int off=1; off<256; off<<=1){
    int a = (tid >= off) ? s[tid-off] : 0;
    __syncthreads();
    s[tid] += a;
    __syncthreads();
  }
  starts[bh*256 + tid] = s[tid] - v;
}

// ---------------- K3b: stable counting-sort scatter ----------------
__global__ __launch_bounds__(64) void k3b_scatter(const unsigned short* __restrict__ bucket,
    const int* __restrict__ starts, int* __restrict__ st)
{
  int blk = blockIdx.x;
  int bh = blk >> 8; int g = blk & 255; int h = g >> 6;
  int lane = threadIdx.x;
  const unsigned short* brow = bucket + ((bh*NHASH + h)<<12);
  int base = starts[bh*NBUCK + g];
  for (int step=0; step<64; step++){
    int t = step*64 + lane;
    bool pred = (brow[t] == (unsigned short)g);
    unsigned long long mask = __ballot(pred);
    if (pred){
      int off = __popcll(mask & ((1ull<<lane) - 1ull));
      st[bh*TOT + base + off] = t;
    }
    base += __popcll(mask);
  }
}

// ---------------- K4: MFMA chunked LSH attention ------------------------------
// 4 cooperative waves per chunk (wave w owns query sub-tile mi=w).
// 36864B LDS -> 4 blocks/CU at 256 thr = 16 waves/CU. XCD-aware swizzle.
__global__ __launch_bounds__(256, 4) void k4_attn(const f16* __restrict__ qk16,
    const f16* __restrict__ v16, const int* __restrict__ st,
    float* __restrict__ lse_out, f16* __restrict__ o_out)
{
  __shared__ __align__(16) char smem[36864];
  f16*   k_lds   = (f16*)smem;                 // 128 x KSTRIDE (alias p_lds)
  f16*   p_lds   = (f16*)smem;                 // 64 x PSTRIDE
  f16*   vT      = (f16*)(smem + 18432);       // 64 x PSTRIDE (d-major)
  float* invnorm = (float*)(smem + 35840);
  int*   kv_t    = (int*)(smem + 36352);

  int bid = blockIdx.x;
  int swz = (bid & 7) * 1024 + (bid >> 3);     // bijective: 8192 = 8*1024
  int bh = swz >> 8; int c = swz & 255;
  int h = c >> 6; int cp = (c + 255) & 255;
  int tid = threadIdx.x;
  int w = tid >> 6, lane = tid & 63;
  int c_lane = lane & 15, quad = lane >> 4;
  const int* strow = st + bh*TOT;

  // ---- load phase: threads 0..127, one full K/V row each
  if (tid < 128){
    int row = tid;
    int slot = (row < 64) ? (c*64 + row) : (cp*64 + row - 64);
    int t = strow[slot];
    kv_t[row] = t;
    const f16x8* kr = (const f16x8*)(qk16 + ((size_t)bh*T_SZ + t)*DH);
    const f16x8* vr = (const f16x8*)(v16  + ((size_t)bh*T_SZ + t)*DH);
    f16x8 kv[8], vv[8];
    float ss = 0.f;
    #pragma unroll
    for (int i=0;i<8;i++){
      f16x8 x = kr[i]; kv[i] = x;
      vv[i] = vr[i];
      #pragma unroll
      for (int e=0;e<8;e++){ float f = (float)x[e]; ss += f*f; }
    }
    invnorm[row] = 1.0f / fmaxf(sqrtf(ss), 1e-12f);
    f16x8* kd = (f16x8*)&k_lds[row*KSTRIDE];
    #pragma unroll
    for (int i=0;i<8;i++) kd[i] = kv[i];
    #pragma unroll
    for (int i=0;i<8;i++){
      #pragma unroll
      for (int e=0;e<8;e++) vT[(i*8+e)*PSTRIDE + row] = vv[i][e];
    }
  }
  __syncthreads();

  // ---- QK^T: wave w computes query sub-tile mi = w ----
  int mi = w;
  f16x8 aq[2];
  #pragma unroll
  for (int kb=0;kb<2;kb++)
    aq[kb] = *(const f16x8*)&k_lds[(mi*16 + c_lane)*KSTRIDE + kb*32 + quad*8];

  f32x4 accS[8];
  #pragma unroll
  for (int ni=0;ni<8;ni++) accS[ni] = (f32x4){0.f,0.f,0.f,0.f};

  #pragma unroll
  for (int ni=0;ni<8;ni++){
    int rowb = ni*16 + c_lane;
    f16 sc = (f16)invnorm[rowb];
    f16x8 b0 = *(const f16x8*)&k_lds[rowb*KSTRIDE + 0*32 + quad*8];
    f16x8 b1 = *(const f16x8*)&k_lds[rowb*KSTRIDE + 1*32 + quad*8];
    b0 *= sc; b1 *= sc;
    accS[ni] = __builtin_amdgcn_mfma_f32_16x16x32_f16(aq[0], b0, accS[ni], 0,0,0);
    accS[ni] = __builtin_amdgcn_mfma_f32_16x16x32_f16(aq[1], b1, accS[ni], 0,0,0);
  }

  int tq[4];
  #pragma unroll
  for (int r=0;r<4;r++) tq[r] = kv_t[mi*16 + quad*4 + r];
  int tk[8];
  #pragma unroll
  for (int ni=0;ni<8;ni++) tk[ni] = kv_t[ni*16 + c_lane];

  float mrow[4], lrow[4];
  #pragma unroll
  for (int r=0;r<4;r++){
    float mx = -1e30f;
    #pragma unroll
    for (int ni=0;ni<8;ni++){
      float s = accS[ni][r] * 0.125f;
      if (tk[ni] == tq[r]) s = -50000.0f;
      accS[ni][r] = s;
      mx = fmaxf(mx, s);
    }
    mx = fmaxf(mx, __shfl_xor(mx, 1));
    mx = fmaxf(mx, __shfl_xor(mx, 2));
    mx = fmaxf(mx, __shfl_xor(mx, 4));
    mx = fmaxf(mx, __shfl_xor(mx, 8));
    mrow[r] = mx;
    float ls = 0.f;
    #pragma unroll
    for (int ni=0;ni<8;ni++){
      float e = __expf(accS[ni][r] - mx);
      accS[ni][r] = e;
      ls += e;
    }
    ls += __shfl_xor(ls, 1);
    ls += __shfl_xor(ls, 2);
    ls += __shfl_xor(ls, 4);
    ls += __shfl_xor(ls, 8);
    lrow[r] = ls;
  }

  // all waves done reading k_lds (aliased with p_lds) before any P write
  __syncthreads();

  #pragma unroll
  for (int ni=0;ni<8;ni++)
    #pragma unroll
    for (int r=0;r<4;r++)
      p_lds[(mi*16 + quad*4 + r)*PSTRIDE + ni*16 + c_lane] = (f16)accS[ni][r];

  // wave reads only its own P rows -> no cross-wave barrier needed
  f16x8 pa[4];
  #pragma unroll
  for (int kb=0;kb<4;kb++)
    pa[kb] = *(const f16x8*)&p_lds[(mi*16 + c_lane)*PSTRIDE + kb*32 + quad*8];

  size_t rowbase = (size_t)(bh*NHASH + h)*T_SZ;
  #pragma unroll
  for (int ni2=0;ni2<4;ni2++){
    f16x8 bv[4];
    #pragma unroll
    for (int kb=0;kb<4;kb++)
      bv[kb] = *(const f16x8*)&vT[(ni2*16 + c_lane)*PSTRIDE + kb*32 + quad*8];
    f32x4 accO = (f32x4){0.f,0.f,0.f,0.f};
    #pragma unroll
    for (int kb=0;kb<4;kb++)
      accO = __builtin_amdgcn_mfma_f32_16x16x32_f16(pa[kb], bv[kb], accO, 0,0,0);
    #pragma unroll
    for (int r=0;r<4;r++){
      float invl = 1.0f / lrow[r];
      f16* orow = o_out + (rowbase + tq[r])*DH;
      orow[ni2*16 + c_lane] = (f16)(accO[r] * invl);
    }
  }
  #pragma unroll
  for (int r=0;r<4;r++){
    if (c_lane == 0)
      lse_out[rowbase + tq[r]] = mrow[r] + logf(lrow[r]);
  }
}

// ---------------- launch ----------------
extern "C" void kernel_launch(void* const* d_in, const int* in_sizes, int n_in,
                              void* d_out, int out_size, void* d_ws, size_t ws_size,
                              hipStream_t stream) {
  const float* queries = (const float*)d_in[0];
  const float* Wqk     = (const float*)d_in[3];
  const float* Wv      = (const float*)d_in[4];
  const float* Wout    = (const float*)d_in[5];
  const float* bout    = (const float*)d_in[6];
  const float* rot     = (const float*)d_in[7];
  float* out = (float*)d_out;

  const size_t SZ_F16  = (size_t)BH*T_SZ*DH*2;        // 16 MB
  const size_t SZ_WT   = (size_t)1536*512*2;          // 1.5 MB
  const size_t SZ_ROT  = (size_t)128*64*2;            // 16 KB
  const size_t SZ_O    = (size_t)BH*NHASH*T_SZ*DH*2;  // 64 MB
  const size_t OFS_X      = 0;
  const size_t OFS_AH     = OFS_X    + 2*SZ_F16;
  const size_t OFS_AL     = OFS_AH   + SZ_F16;
  const size_t OFS_QK16   = OFS_AL   + SZ_F16;
  const size_t OFS_V16    = OFS_QK16 + SZ_F16;
  const size_t OFS_WTH    = OFS_V16  + SZ_F16;
  const size_t OFS_WTL    = OFS_WTH  + SZ_WT;
  const size_t OFS_ROTH   = OFS_WTL  + SZ_WT;
  const size_t OFS_ROTL   = OFS_ROTH + SZ_ROT;
  const size_t OFS_O      = OFS_ROTL + SZ_ROT;
  const size_t OFS_BUCKET = OFS_O    + SZ_O;
  const size_t OFS_HIST   = OFS_BUCKET + (size_t)BH*NHASH*T_SZ*2;
  const size_t OFS_STARTS = OFS_HIST   + (size_t)BH*NBUCK*4;
  const size_t OFS_ST     = OFS_STARTS + (size_t)BH*NBUCK*4;
  const size_t OFS_LSE    = OFS_ST     + (size_t)BH*TOT*4;
  const size_t OFS_AMB    = OFS_LSE    + (size_t)BH*NHASH*T_SZ*4;
  const size_t OFS_CNT    = OFS_AMB    + (size_t)BH*NHASH*T_SZ*4;
  const size_t WS_NEEDED  = OFS_CNT    + 256;
  if (ws_size < WS_NEEDED) return;

  char* ws = (char*)d_ws;
  f16*      qkl    = (f16*)(ws + OFS_X);               // lo split of qk (g_qkv/k2)
  f16*      Ah     = (f16*)(ws + OFS_AH);
  f16*      Al     = (f16*)(ws + OFS_AL);
  f16*      qk16   = (f16*)(ws + OFS_QK16);
  f16*      v16    = (f16*)(ws + OFS_V16);
  f16*      Wth    = (f16*)(ws + OFS_WTH);
  f16*      Wtl    = (f16*)(ws + OFS_WTL);
  f16*      rotTh  = (f16*)(ws + OFS_ROTH);
  f16*      rotTl  = (f16*)(ws + OFS_ROTL);
  f16*      o_f16  = (f16*)(ws + OFS_O);
  unsigned short* bucket = (unsigned short*)(ws + OFS_BUCKET);
  int*      starts = (int*)(ws + OFS_STARTS);
  int*      st     = (int*)(ws + OFS_ST);
  float*    lse    = (float*)(ws + OFS_LSE);
  int*      amb    = (int*)(ws + OFS_AMB);
  int*      cnt    = (int*)(ws + OFS_CNT);

  kprep     <<<7200, 256, 0, stream>>>(Wqk, Wv, Wout, Wth, Wtl, rot, rotTh, rotTl,
                                       queries, Ah, Al, cnt);
  g_qkv     <<<dim3(M_TOK/128, 8), 256, 0, stream>>>(Ah, Al, Wth, Wtl, qk16, qkl, v16);
  k2_mfma   <<<(BH*T_SZ)/64, 256, 0, stream>>>(qk16, qkl, rotTh, rotTl, bucket, amb, cnt);
  k2_fix    <<<2048, 256, 0, stream>>>(queries, Wqk, rot, amb, cnt, bucket);
  k3_scan   <<<BH, 256, 0, stream>>>(bucket, starts);
  k3b_scatter<<<BH*NBUCK, 64, 0, stream>>>(bucket, starts, st);
  k4_attn   <<<BH*256, 256, 0, stream>>>(qk16, v16, st, lse, o_f16);
  g_out     <<<dim3(M_TOK/128, 4), 256, 0, stream>>>(lse, o_f16, Wth, Wtl, bout, out);
}